// Round 9
// baseline (245.577 us; speedup 1.0000x reference)
//
#include <hip/hip_runtime.h>
#include <hip/hip_bf16.h>
#include <stdint.h>

#define HID   1024
#define NH    16
#define HD    64
#define BATCH 2
#define SEQ   2048
#define MROWS (BATCH*SEQ)
// Q is pre-scaled by ATT_SCALE*log2(e) in the QKV epilogue; softmax uses exp2.
#define QPRESCALE 0.18033688f          // 0.125 * 1.4426950408889634
#define MASK_L2E  (-14426.950408889634f)  // -10000 * log2(e)

typedef __attribute__((ext_vector_type(4))) float f32x4;
typedef __attribute__((ext_vector_type(8))) short bf16x8;
typedef unsigned short u16;
typedef __attribute__((ext_vector_type(4))) unsigned short u16x4;

// fp32 -> bf16 round-to-nearest-even, raw bits
__device__ __forceinline__ u16 f2b(float f) {
  union { float f; unsigned u; } c; c.f = f;
  unsigned u = c.u;
  return (u16)((u + 0x7fffu + ((u >> 16) & 1u)) >> 16);
}

// packed f32x2 -> bf16x2 via documented HIP API (guaranteed packing: x=lo, y=hi)
__device__ __forceinline__ unsigned pk2(float a, float b) {
  union { __hip_bfloat162 h; unsigned u; } c;
  c.h = __float22bfloat162_rn(make_float2(a, b));
  return c.u;
}

// async global -> LDS, 16 bytes per lane (wave-uniform LDS base + lane*16)
__device__ __forceinline__ void gload16(const void* g, void* l) {
  __builtin_amdgcn_global_load_lds((__attribute__((address_space(1))) void*)g,
                                   (__attribute__((address_space(3))) void*)l,
                                   16, 0, 0);
}

// ---------------------------------------------------------------- cast X
__global__ void castx_kernel(const float* __restrict__ X, u16* __restrict__ XB) {
  const int i = blockIdx.x * blockDim.x + threadIdx.x;
  const float4 v = ((const float4*)X)[i];
  u16x4 o = { f2b(v.x), f2b(v.y), f2b(v.z), f2b(v.w) };
  ((u16x4*)XB)[i] = o;
}

// ------------------------------------------------- transpose-cast 4x W -> W^T
__global__ void wtrans4_kernel(const float* w0, const float* w1,
                               const float* w2, const float* w3,
                               u16* o0, u16* o1, u16* o2, u16* o3) {
  __shared__ u16 tile[32][33];
  const int z = blockIdx.z;
  const float* __restrict__ W = (z == 0) ? w0 : (z == 1) ? w1 : (z == 2) ? w2 : w3;
  u16* __restrict__ Wt = (z == 0) ? o0 : (z == 1) ? o1 : (z == 2) ? o2 : o3;
  const int bx = blockIdx.x * 32;  // n base (cols of W)
  const int by = blockIdx.y * 32;  // k base (rows of W)
  const int tx = threadIdx.x, ty = threadIdx.y;
#pragma unroll
  for (int i = 0; i < 4; ++i)
    tile[ty + i * 8][tx] = f2b(W[(size_t)(by + ty + i * 8) * HID + bx + tx]);
  __syncthreads();
#pragma unroll
  for (int i = 0; i < 4; ++i)
    Wt[(size_t)(bx + ty + i * 8) * HID + by + tx] = tile[tx][ty + i * 8];
}

// ------------------------------------------------------- fused QKV GEMM
// 256x256 tile, 8 waves (2M x 4N, 128x64 per wave), BK=64, 2-phase dbuf
// (STAGE next K-tile before compute; single barrier per step — r6-attn
// pattern; at ~1 block/CU dbuf is the only latency hiding available).
// A: [MROWS][HID] bf16. Bt: [3072][HID] bf16 (WTq|WTk|WTv contiguous).
// n in [0,1024) -> Q*QPRESCALE [B,NH,S,HD]; [1024,2048) -> K same layout;
// [2048,3072) -> V^T [B,NH,HD,S]. XCD swizzle: nwg=192, q=24.
__global__ __launch_bounds__(512) void gemm_qkv_kernel(const u16* __restrict__ A,
                                                       const u16* __restrict__ Bt,
                                                       const float* __restrict__ bq,
                                                       const float* __restrict__ bk,
                                                       const float* __restrict__ bv,
                                                       u16* __restrict__ Qb,
                                                       u16* __restrict__ Kb,
                                                       u16* __restrict__ VTb) {
  __shared__ u16 Asm[2][256 * 64];   // 32KB x2
  __shared__ u16 Bsm[2][256 * 64];   // 32KB x2   (total 128KB)
  const int tid = threadIdx.x;
  const int lane = tid & 63;
  const int wid = tid >> 6;          // 0..7
  const int wr = wid >> 2;           // 0..1 : 128 m-rows each
  const int wc = wid & 3;            // 0..3 : 64 n-cols each
  // bijective XCD swizzle (192 % 8 == 0): XCD k gets work [k*24, k*24+24)
  const int work = (blockIdx.x & 7) * 24 + (blockIdx.x >> 3);
  const int mx = work & 15;          // M fast-varying: B-panels L2-resident/XCD
  const int ny = work >> 4;          // 0..11
  const int m0 = mx * 256;
  const int n0 = ny * 256;
  const int mat = n0 >> 10;          // 0=Q 1=K 2=V (256 | 1024 boundaries)
  const int lrow = lane & 15;
  const int kgrp = (lane >> 4) * 8;

  f32x4 acc[8][4];
#pragma unroll
  for (int i = 0; i < 8; ++i)
#pragma unroll
    for (int j = 0; j < 4; ++j)
#pragma unroll
      for (int r = 0; r < 4; ++r) acc[i][j][r] = 0.f;

  auto STAGE = [&](int kt, int bufi) {
#pragma unroll
    for (int it = 0; it < 4; ++it) {
      const int off = it * 8192 + tid * 16;   // byte offset in 32KB tile
      const int row = off >> 7;               // 128B per row
      const int col = (off & 127) >> 1;       // ushort col
      gload16(A  + (size_t)(m0 + row) * HID + kt * 64 + col, (char*)Asm[bufi] + off);
      gload16(Bt + (size_t)(n0 + row) * HID + kt * 64 + col, (char*)Bsm[bufi] + off);
    }
  };

  STAGE(0, 0);
  __syncthreads();   // vmcnt(0) drain: tile 0 resident

  const int NKT = HID / 64;
  for (int kt = 0; kt < NKT; ++kt) {
    const int cur = kt & 1;
    if (kt + 1 < NKT) STAGE(kt + 1, cur ^ 1);

    const u16* Ac = Asm[cur];
    const u16* Bc = Bsm[cur];
#pragma unroll
    for (int kk = 0; kk < 2; ++kk) {
      bf16x8 af[8], bfr[4];
#pragma unroll
      for (int i = 0; i < 8; ++i)
        af[i]  = *(const bf16x8*)(Ac + (size_t)(wr * 128 + i * 16 + lrow) * 64 + kk * 32 + kgrp);
#pragma unroll
      for (int j = 0; j < 4; ++j)
        bfr[j] = *(const bf16x8*)(Bc + (size_t)(wc * 64 + j * 16 + lrow) * 64 + kk * 32 + kgrp);
#pragma unroll
      for (int i = 0; i < 8; ++i)
#pragma unroll
        for (int j = 0; j < 4; ++j)
          acc[i][j] = __builtin_amdgcn_mfma_f32_16x16x32_bf16(af[i], bfr[j], acc[i][j], 0, 0, 0);
    }
    __syncthreads();   // next tile resident; cur free for overwrite next iter
  }

  const float* bias = (mat == 0) ? bq : (mat == 1) ? bk : bv;
  u16* O = (mat == 0) ? Qb : (mat == 1) ? Kb : VTb;
  const float qs = (mat == 0) ? QPRESCALE : 1.0f;
#pragma unroll
  for (int i = 0; i < 8; ++i) {
#pragma unroll
    for (int j = 0; j < 4; ++j) {
      const int rbase = m0 + wr * 128 + i * 16 + (lane >> 4) * 4;
      const int n = n0 + wc * 64 + j * 16 + lrow;
      const int nl = n & 1023;
      const float bv_ = bias[nl];
      const int h = nl >> 6, d = nl & 63;
      if (mat != 2) {
#pragma unroll
        for (int r = 0; r < 4; ++r) {
          const int m = rbase + r;
          const int b = m >> 11, s = m & 2047;
          O[((size_t)(b * NH + h) * SEQ + s) * HD + d] = f2b((acc[i][j][r] + bv_) * qs);
        }
      } else {  // V^T  [B,NH,HD,S]
        const int b = rbase >> 11, s = rbase & 2047;
        u16x4 pk;
#pragma unroll
        for (int r = 0; r < 4; ++r) pk[r] = f2b(acc[i][j][r] + bv_);
        *(u16x4*)(O + ((size_t)(b * NH + h) * HD + d) * SEQ + s) = pk;
      }
    }
  }
}

// ---------------------------------------------------------------- out GEMM
// 128x128 tile (256 blocks = 1/CU), 2-phase dbuf, XCD swizzle (q=32).
// A: [MROWS][HID] bf16 (ctx). Bt: [HID][HID] bf16 (Wo^T). fp32 out.
__global__ __launch_bounds__(256) void gemm_out_kernel(const u16* __restrict__ A,
                                                       const u16* __restrict__ Bt,
                                                       const float* __restrict__ bias,
                                                       float* __restrict__ O) {
  __shared__ u16 Asm[2][128 * 64];
  __shared__ u16 Bsm[2][128 * 64];
  const int tid = threadIdx.x;
  const int lane = tid & 63;
  const int wid = tid >> 6;
  const int wr = wid >> 1, wc = wid & 1;
  const int work = (blockIdx.x & 7) * 32 + (blockIdx.x >> 3);  // 256 % 8 == 0
  const int m0 = (work & 31) * 128;   // M fast: B-panel resident per XCD
  const int n0 = (work >> 5) * 128;
  const int lrow = lane & 15;
  const int kgrp = (lane >> 4) * 8;

  f32x4 acc[4][4];
#pragma unroll
  for (int i = 0; i < 4; ++i)
#pragma unroll
    for (int j = 0; j < 4; ++j)
#pragma unroll
      for (int r = 0; r < 4; ++r) acc[i][j][r] = 0.f;

  auto STAGE = [&](int kt, int bufi) {
#pragma unroll
    for (int it = 0; it < 4; ++it) {
      const int off = it * 4096 + tid * 16;
      const int row = off >> 7;
      const int col = (off & 127) >> 1;
      gload16(A  + (size_t)(m0 + row) * HID + kt * 64 + col, (char*)Asm[bufi] + off);
      gload16(Bt + (size_t)(n0 + row) * HID + kt * 64 + col, (char*)Bsm[bufi] + off);
    }
  };

  STAGE(0, 0);
  __syncthreads();

  const int NKT = HID / 64;
  for (int kt = 0; kt < NKT; ++kt) {
    const int cur = kt & 1;
    if (kt + 1 < NKT) STAGE(kt + 1, cur ^ 1);

    const u16* Ac = Asm[cur];
    const u16* Bc = Bsm[cur];
#pragma unroll
    for (int kk = 0; kk < 2; ++kk) {
      bf16x8 af[4], bfr[4];
#pragma unroll
      for (int i = 0; i < 4; ++i) {
        af[i]  = *(const bf16x8*)(Ac + (size_t)(wr * 64 + i * 16 + lrow) * 64 + kk * 32 + kgrp);
        bfr[i] = *(const bf16x8*)(Bc + (size_t)(wc * 64 + i * 16 + lrow) * 64 + kk * 32 + kgrp);
      }
#pragma unroll
      for (int i = 0; i < 4; ++i)
#pragma unroll
        for (int j = 0; j < 4; ++j)
          acc[i][j] = __builtin_amdgcn_mfma_f32_16x16x32_bf16(af[i], bfr[j], acc[i][j], 0, 0, 0);
    }
    __syncthreads();
  }

#pragma unroll
  for (int i = 0; i < 4; ++i) {
#pragma unroll
    for (int j = 0; j < 4; ++j) {
      const int rbase = m0 + wr * 64 + i * 16 + (lane >> 4) * 4;
      const int n = n0 + wc * 64 + j * 16 + lrow;
      const float bv = bias[n];
#pragma unroll
      for (int r = 0; r < 4; ++r)
        O[(size_t)(rbase + r) * HID + n] = acc[i][j][r] + bv;
    }
  }
}

// ------------------------------------------------------------ flash attention
// r6 version (measured best: 84.0 us, conflicts 1.05e6).
// Q (pre-scaled by QPRESCALE), K: [B,NH,S,HD] bf16; Vt: [B,NH,HD,S] bf16;
// msk: [B,S] f32; ctx out: [B,S,HID] bf16
// QBLK=128 (512 blocks). XCD-confined head mapping (r5: FETCH 69.7->12.3MB).
// Double-buffered K/V staging; fixed-max exp2 softmax; ones-MFMA row-sum;
// XOR-swizzled K/V LDS (byte ^= (row&7)<<4) via pre-swizzled global src.
__global__ __launch_bounds__(256) void attn_kernel(const u16* __restrict__ Q,
                                                   const u16* __restrict__ K,
                                                   const u16* __restrict__ Vt,
                                                   const float* __restrict__ msk,
                                                   u16* __restrict__ ctx) {
  __shared__ u16 Ks[2][64 * 64];    // [buf][key][d], swizzled
  __shared__ u16 Vs[2][64 * 64];    // [buf][d][key], swizzled
  __shared__ u16 Ps[4][32 * 72];    // per-wave P (32 q-rows), padded rows
  const int bid = blockIdx.x;
  const int xcd = bid & 7;
  const int idx = bid >> 3;               // 0..63
  const int bh = xcd * 4 + (idx & 3);     // head group confined to this XCD
  const int q0 = (idx >> 2) * 128;        // 16 q-tiles of 128 rows
  const int b = bh >> 4, h = bh & 15;
  const int tid = threadIdx.x, lane = tid & 63, wid = tid >> 6;
  const int lrow = lane & 15;
  const int kgrp = (lane >> 4) * 8;
  const u16* Qp = Q + (size_t)bh * SEQ * HD;
  const u16* Kp = K + (size_t)bh * SEQ * HD;
  const u16* Vp = Vt + (size_t)bh * HD * SEQ;

  // ones B-fragment (bf16 1.0) for row-sum MFMA
  bf16x8 vones;
#pragma unroll
  for (int i = 0; i < 8; ++i) vones[i] = (short)0x3F80;

  // Q fragments in registers, reused for all key tiles. Wave owns 32 q-rows.
  bf16x8 qf[2][2];
#pragma unroll
  for (int rf = 0; rf < 2; ++rf)
#pragma unroll
    for (int kk = 0; kk < 2; ++kk)
      qf[rf][kk] = *(const bf16x8*)(Qp + (size_t)(q0 + wid * 32 + rf * 16 + lrow) * HD + kk * 32 + kgrp);

  f32x4 acc[2][4], acc_l[2];
#pragma unroll
  for (int rf = 0; rf < 2; ++rf) {
#pragma unroll
    for (int r = 0; r < 4; ++r) acc_l[rf][r] = 0.f;
#pragma unroll
    for (int df = 0; df < 4; ++df)
#pragma unroll
      for (int r = 0; r < 4; ++r) acc[rf][df][r] = 0.f;
  }

  // stage K/V tile for keys [s0, s0+64) into buffer bufi
  auto STAGE = [&](int s0, int bufi) {
#pragma unroll
    for (int it = 0; it < 2; ++it) {
      const int off = it * 4096 + tid * 16;
      const int row = off >> 7;
      const int w = off & 127;
      const int col = (w ^ ((row & 7) << 4)) >> 1;   // inverse-swizzled source
      gload16(Kp + (size_t)(s0 + row) * HD + col, (char*)Ks[bufi] + off);
      gload16(Vp + (size_t)row * SEQ + s0 + col, (char*)Vs[bufi] + off);
    }
  };

  STAGE(0, 0);
  __syncthreads();   // drains vmcnt(0): tile 0 resident

  const int NT = SEQ / 64;
  for (int t = 0; t < NT; ++t) {
    const int cur = t & 1;
    if (t + 1 < NT) STAGE((t + 1) * 64, cur ^ 1);   // prefetch next tile

    const u16* Kc = Ks[cur];
    const u16* Vc = Vs[cur];
    const int s0 = t * 64;

    // S' = Qs K^T  (log2e*scale already folded into Q)
    f32x4 sf[2][4];
#pragma unroll
    for (int rf = 0; rf < 2; ++rf)
#pragma unroll
      for (int c = 0; c < 4; ++c)
#pragma unroll
        for (int r = 0; r < 4; ++r) sf[rf][c][r] = 0.f;
#pragma unroll
    for (int kk = 0; kk < 2; ++kk) {
      bf16x8 kf[4];
#pragma unroll
      for (int c = 0; c < 4; ++c) {
        const int row = c * 16 + lrow;
        const int byteoff = row * 128 + ((kk * 64 + (lane >> 4) * 16) ^ ((row & 7) << 4));
        kf[c] = *(const bf16x8*)((const char*)Kc + byteoff);
      }
#pragma unroll
      for (int rf = 0; rf < 2; ++rf)
#pragma unroll
        for (int c = 0; c < 4; ++c)
          sf[rf][c] = __builtin_amdgcn_mfma_f32_16x16x32_bf16(qf[rf][kk], kf[c], sf[rf][c], 0, 0, 0);
    }

    // additive mask in log2 domain (column-wise)
    float addm[4];
#pragma unroll
    for (int c = 0; c < 4; ++c)
      addm[c] = (1.0f - msk[b * SEQ + s0 + c * 16 + lrow]) * MASK_L2E;

    // fixed-max softmax: P = exp2(S' + mask'); write bf16 P to per-wave LDS
#pragma unroll
    for (int rf = 0; rf < 2; ++rf) {
#pragma unroll
      for (int c = 0; c < 4; ++c)
#pragma unroll
        for (int r = 0; r < 4; ++r)
          sf[rf][c][r] = __builtin_exp2f(sf[rf][c][r] + addm[c]);
#pragma unroll
      for (int r = 0; r < 4; ++r) {
        const int row = rf * 16 + (lane >> 4) * 4 + r;
        const unsigned w01 = pk2(sf[rf][0][r], sf[rf][1][r]);
        const unsigned w23 = pk2(sf[rf][2][r], sf[rf][3][r]);
        u16* base = &Ps[wid][(size_t)row * 72 + lrow];
        base[0]  = (u16)w01;
        base[16] = (u16)(w01 >> 16);
        base[32] = (u16)w23;
        base[48] = (u16)(w23 >> 16);
      }
    }

    // ctx += P V ; l += P @ 1  (A-frags re-read from own wave's Ps)
#pragma unroll
    for (int kk = 0; kk < 2; ++kk) {
      bf16x8 pf[2], vf[4];
#pragma unroll
      for (int rf = 0; rf < 2; ++rf)
        pf[rf] = *(const bf16x8*)(&Ps[wid][(size_t)(rf * 16 + lrow) * 72 + kk * 32 + kgrp]);
#pragma unroll
      for (int df = 0; df < 4; ++df) {
        const int row = df * 16 + lrow;
        const int byteoff = row * 128 + ((kk * 64 + (lane >> 4) * 16) ^ ((row & 7) << 4));
        vf[df] = *(const bf16x8*)((const char*)Vc + byteoff);
      }
#pragma unroll
      for (int rf = 0; rf < 2; ++rf) {
#pragma unroll
        for (int df = 0; df < 4; ++df)
          acc[rf][df] = __builtin_amdgcn_mfma_f32_16x16x32_bf16(pf[rf], vf[df], acc[rf][df], 0, 0, 0);
        acc_l[rf] = __builtin_amdgcn_mfma_f32_16x16x32_bf16(pf[rf], vones, acc_l[rf], 0, 0, 0);
      }
    }

    __syncthreads();   // next tile resident (vmcnt drain) + buf^1 free for reuse
  }

  // normalize + store ctx in [B,S,HID] bf16
#pragma unroll
  for (int rf = 0; rf < 2; ++rf) {
    f32x4 rl;
#pragma unroll
    for (int r = 0; r < 4; ++r) rl[r] = 1.0f / acc_l[rf][r];
#pragma unroll
    for (int df = 0; df < 4; ++df)
#pragma unroll
      for (int r = 0; r < 4; ++r) {
        const int s = q0 + wid * 32 + rf * 16 + (lane >> 4) * 4 + r;
        const int d = df * 16 + lrow;
        ctx[((size_t)(b * SEQ + s)) * HID + h * HD + d] = f2b(acc[rf][df][r] * rl[r]);
      }
  }
}

// ---------------------------------------------------------------- launch
extern "C" void kernel_launch(void* const* d_in, const int* in_sizes, int n_in,
                              void* d_out, int out_size, void* d_ws, size_t ws_size,
                              hipStream_t stream) {
  const float* X    = (const float*)d_in[0];
  const float* msk  = (const float*)d_in[1];
  const float* Wq   = (const float*)d_in[2];
  const float* bq   = (const float*)d_in[3];
  const float* Wk   = (const float*)d_in[4];
  const float* bk   = (const float*)d_in[5];
  const float* Wv   = (const float*)d_in[6];
  const float* bv   = (const float*)d_in[7];
  const float* Wo   = (const float*)d_in[8];
  const float* bo   = (const float*)d_in[9];
  float* out = (float*)d_out;
  char* ws = (char*)d_ws;

  const size_t MB = 1u << 20;
  u16* XB   = (u16*)(ws);              //  8 MB  [MROWS][HID]
  u16* WTq  = (u16*)(ws +  8 * MB);    //  2 MB each; WTq|WTk|WTv contiguous
  u16* WTk  = (u16*)(ws + 10 * MB);
  u16* WTv  = (u16*)(ws + 12 * MB);
  u16* WTo  = (u16*)(ws + 14 * MB);
  u16* Qb   = (u16*)(ws + 16 * MB);    //  8 MB  [B,NH,S,HD] (pre-scaled)
  u16* Kb   = (u16*)(ws + 24 * MB);    //  8 MB  [B,NH,S,HD]
  u16* VTb  = (u16*)(ws + 32 * MB);    //  8 MB  [B,NH,HD,S]
  u16* CTXb = (u16*)(ws + 40 * MB);    //  8 MB  [B,S,HID]

  castx_kernel<<<dim3(MROWS * HID / 4 / 256), dim3(256), 0, stream>>>(X, XB);
  wtrans4_kernel<<<dim3(HID / 32, HID / 32, 4), dim3(32, 8), 0, stream>>>(
      Wq, Wk, Wv, Wo, WTq, WTk, WTv, WTo);

  // 256x256 tiles: (4096/256) x (3072/256) = 16 x 12 = 192 blocks, 512 thr
  gemm_qkv_kernel<<<dim3(192), dim3(512), 0, stream>>>(
      XB, WTq, bq, bk, bv, Qb, Kb, VTb);

  attn_kernel<<<dim3(512), dim3(256), 0, stream>>>(Qb, Kb, VTb, msk, CTXb);

  // 128x128 tiles: 32 x 8 = 256 blocks
  gemm_out_kernel<<<dim3(256), dim3(256), 0, stream>>>(CTXb, WTo, bo, out);
}

// Round 10
// 231.241 us; speedup vs baseline: 1.0620x; 1.0620x over previous
//
#include <hip/hip_runtime.h>
#include <hip/hip_bf16.h>
#include <stdint.h>

#define HID   1024
#define NH    16
#define HD    64
#define BATCH 2
#define SEQ   2048
#define MROWS (BATCH*SEQ)
// Q is pre-scaled by ATT_SCALE*log2(e) in the QKV epilogue; softmax uses exp2.
#define QPRESCALE 0.18033688f          // 0.125 * 1.4426950408889634
#define MASK_L2E  (-14426.950408889634f)  // -10000 * log2(e)

typedef __attribute__((ext_vector_type(4))) float f32x4;
typedef __attribute__((ext_vector_type(8))) short bf16x8;
typedef unsigned short u16;
typedef __attribute__((ext_vector_type(4))) unsigned short u16x4;

__device__ __forceinline__ u16 f2b(float f) {
  union { float f; unsigned u; } c; c.f = f;
  unsigned u = c.u;
  return (u16)((u + 0x7fffu + ((u >> 16) & 1u)) >> 16);
}

__device__ __forceinline__ unsigned pk2(float a, float b) {
  union { __hip_bfloat162 h; unsigned u; } c;
  c.h = __float22bfloat162_rn(make_float2(a, b));
  return c.u;
}

__device__ __forceinline__ void gload16(const void* g, void* l) {
  __builtin_amdgcn_global_load_lds((__attribute__((address_space(1))) void*)g,
                                   (__attribute__((address_space(3))) void*)l,
                                   16, 0, 0);
}

#define VM0()   asm volatile("s_waitcnt vmcnt(0)" ::: "memory")
#define LGKM0() asm volatile("s_waitcnt lgkmcnt(0)" ::: "memory")
#define BAR()   __builtin_amdgcn_s_barrier()

// ---------------------------------------------------------------- cast X
__global__ void castx_kernel(const float* __restrict__ X, u16* __restrict__ XB) {
  const int i = blockIdx.x * blockDim.x + threadIdx.x;
  const float4 v = ((const float4*)X)[i];
  u16x4 o = { f2b(v.x), f2b(v.y), f2b(v.z), f2b(v.w) };
  ((u16x4*)XB)[i] = o;
}

// ------------------------------------------------- transpose-cast 4x W -> W^T
__global__ void wtrans4_kernel(const float* w0, const float* w1,
                               const float* w2, const float* w3,
                               u16* o0, u16* o1, u16* o2, u16* o3) {
  __shared__ u16 tile[32][33];
  const int z = blockIdx.z;
  const float* __restrict__ W = (z == 0) ? w0 : (z == 1) ? w1 : (z == 2) ? w2 : w3;
  u16* __restrict__ Wt = (z == 0) ? o0 : (z == 1) ? o1 : (z == 2) ? o2 : o3;
  const int bx = blockIdx.x * 32;
  const int by = blockIdx.y * 32;
  const int tx = threadIdx.x, ty = threadIdx.y;
#pragma unroll
  for (int i = 0; i < 4; ++i)
    tile[ty + i * 8][tx] = f2b(W[(size_t)(by + ty + i * 8) * HID + bx + tx]);
  __syncthreads();
#pragma unroll
  for (int i = 0; i < 4; ++i)
    Wt[(size_t)(bx + ty + i * 8) * HID + by + tx] = tile[tx][ty + i * 8];
}

// ------------------------------------------------------- fused QKV GEMM
// 256x256 tile, 8 waves (2M x 4N; 128x64 per wave), BK=64, double-buffered,
// 4-phase/K-tile schedule (m198/m201-derived): per phase {stage half-tile
// early | 8x ds_read | BAR; lgkmcnt(0); setprio(1); 16 MFMA; setprio(0); BAR}.
// All 8 prefetch loads issued in phases 0-1; single vmcnt(0) at tile end has
// ~3 phases of slack. LDS XOR-swizzle byte ^= (row&7)<<4 (read 16-way -> 2-way).
// A: [MROWS][HID] bf16. Bt: [3072][HID] bf16. XCD swizzle (192 % 8 == 0).
__global__ __launch_bounds__(512) void gemm_qkv_kernel(const u16* __restrict__ A,
                                                       const u16* __restrict__ Bt,
                                                       const float* __restrict__ bq,
                                                       const float* __restrict__ bk,
                                                       const float* __restrict__ bv,
                                                       u16* __restrict__ Qb,
                                                       u16* __restrict__ Kb,
                                                       u16* __restrict__ VTb) {
  __shared__ u16 Asm[2][256 * 64];   // 32KB x2
  __shared__ u16 Bsm[2][256 * 64];   // 32KB x2
  const int tid = threadIdx.x;
  const int lane = tid & 63;
  const int wid = tid >> 6;
  const int wr = wid >> 2;           // 0..1
  const int wc = wid & 3;            // 0..3
  const int work = (blockIdx.x & 7) * 24 + (blockIdx.x >> 3);
  const int mx = work & 15;
  const int ny = work >> 4;
  const int m0 = mx * 256;
  const int n0 = ny * 256;
  const int mat = n0 >> 10;
  const int lrow = lane & 15;
  const int kgrp = (lane >> 4) * 8;

  f32x4 acc[8][4];
#pragma unroll
  for (int i = 0; i < 8; ++i)
#pragma unroll
    for (int j = 0; j < 4; ++j)
#pragma unroll
      for (int r = 0; r < 4; ++r) acc[i][j][r] = 0.f;

  // stage one 128x64 half-tile (16KB): which 0/1 = A halves, 2/3 = B halves.
  // LDS dest linear; global source column pre-(inverse)-swizzled.
  auto SHALF = [&](int which, int kt, int bufi) {
    const u16* src = (which < 2) ? A : Bt;
    const int gbase = ((which < 2) ? m0 : n0) + (which & 1) * 128;
    char* dst = (char*)((which < 2) ? Asm[bufi] : Bsm[bufi]) + (which & 1) * 16384;
#pragma unroll
    for (int it = 0; it < 2; ++it) {
      const int off = it * 8192 + tid * 16;
      const int row = off >> 7;
      const int col = ((off & 127) ^ ((off >> 3) & 0x70)) >> 1;  // ^(row&7)<<4
      gload16(src + (size_t)(gbase + row) * HID + kt * 64 + col, dst + off);
    }
  };

  // read 4 fragments from swizzled LDS at rowbase + i*16 + lrow, k-half kk
  auto LD4 = [&](const u16* base, int rowbase, int kk, bf16x8* out) {
#pragma unroll
    for (int i = 0; i < 4; ++i) {
      const int row = rowbase + i * 16 + lrow;
      const int adr = (row * 128 + kk * 64 + (lane >> 4) * 16) ^ ((row & 7) << 4);
      out[i] = *(const bf16x8*)((const char*)base + adr);
    }
  };

  // prologue: full tile 0
  SHALF(0, 0, 0); SHALF(1, 0, 0); SHALF(2, 0, 0); SHALF(3, 0, 0);
  VM0();
  BAR();

  const int NKT = HID / 64;
  for (int kt = 0; kt < NKT; ++kt) {
    const int cur = kt & 1;
    const int nxt = cur ^ 1;
    const bool pf = (kt + 1 < NKT);
    bf16x8 af[4], bfr[4];

    // ---- phase 0: stage A halves of kt+1; compute (mh=0, kk=0)
    if (pf) { SHALF(0, kt + 1, nxt); SHALF(1, kt + 1, nxt); }
    LD4(Asm[cur], wr * 128, 0, af);
    LD4(Bsm[cur], wc * 64, 0, bfr);
    BAR(); LGKM0();
    __builtin_amdgcn_s_setprio(1);
#pragma unroll
    for (int i = 0; i < 4; ++i)
#pragma unroll
      for (int j = 0; j < 4; ++j)
        acc[i][j] = __builtin_amdgcn_mfma_f32_16x16x32_bf16(af[i], bfr[j], acc[i][j], 0, 0, 0);
    __builtin_amdgcn_s_setprio(0);
    BAR();

    // ---- phase 1: stage B halves of kt+1; compute (mh=1, kk=0), bfr reused
    if (pf) { SHALF(2, kt + 1, nxt); SHALF(3, kt + 1, nxt); }
    LD4(Asm[cur], wr * 128 + 64, 0, af);
    BAR(); LGKM0();
    __builtin_amdgcn_s_setprio(1);
#pragma unroll
    for (int i = 0; i < 4; ++i)
#pragma unroll
      for (int j = 0; j < 4; ++j)
        acc[4 + i][j] = __builtin_amdgcn_mfma_f32_16x16x32_bf16(af[i], bfr[j], acc[4 + i][j], 0, 0, 0);
    __builtin_amdgcn_s_setprio(0);
    BAR();

    // ---- phase 2: compute (mh=0, kk=1)
    LD4(Asm[cur], wr * 128, 1, af);
    LD4(Bsm[cur], wc * 64, 1, bfr);
    BAR(); LGKM0();
    __builtin_amdgcn_s_setprio(1);
#pragma unroll
    for (int i = 0; i < 4; ++i)
#pragma unroll
      for (int j = 0; j < 4; ++j)
        acc[i][j] = __builtin_amdgcn_mfma_f32_16x16x32_bf16(af[i], bfr[j], acc[i][j], 0, 0, 0);
    __builtin_amdgcn_s_setprio(0);
    BAR();

    // ---- phase 3: compute (mh=1, kk=1); wait tile kt+1 (issued ~3 phases ago)
    LD4(Asm[cur], wr * 128 + 64, 1, af);
    BAR(); LGKM0();
    __builtin_amdgcn_s_setprio(1);
#pragma unroll
    for (int i = 0; i < 4; ++i)
#pragma unroll
      for (int j = 0; j < 4; ++j)
        acc[4 + i][j] = __builtin_amdgcn_mfma_f32_16x16x32_bf16(af[i], bfr[j], acc[4 + i][j], 0, 0, 0);
    __builtin_amdgcn_s_setprio(0);
    VM0();   // tile kt+1 resident before next iteration's reads
    BAR();
  }

  const float* bias = (mat == 0) ? bq : (mat == 1) ? bk : bv;
  u16* O = (mat == 0) ? Qb : (mat == 1) ? Kb : VTb;
  const float qs = (mat == 0) ? QPRESCALE : 1.0f;
#pragma unroll
  for (int i = 0; i < 8; ++i) {
#pragma unroll
    for (int j = 0; j < 4; ++j) {
      const int rbase = m0 + wr * 128 + i * 16 + (lane >> 4) * 4;
      const int n = n0 + wc * 64 + j * 16 + lrow;
      const int nl = n & 1023;
      const float bv_ = bias[nl];
      const int h = nl >> 6, d = nl & 63;
      if (mat != 2) {
#pragma unroll
        for (int r = 0; r < 4; ++r) {
          const int m = rbase + r;
          const int b = m >> 11, s = m & 2047;
          O[((size_t)(b * NH + h) * SEQ + s) * HD + d] = f2b((acc[i][j][r] + bv_) * qs);
        }
      } else {  // V^T  [B,NH,HD,S]
        const int b = rbase >> 11, s = rbase & 2047;
        u16x4 pk;
#pragma unroll
        for (int r = 0; r < 4; ++r) pk[r] = f2b(acc[i][j][r] + bv_);
        *(u16x4*)(O + ((size_t)(b * NH + h) * HD + d) * SEQ + s) = pk;
      }
    }
  }
}

// ---------------------------------------------------------------- out GEMM
// 128x128 tile (256 blocks = 1/CU), 2-phase dbuf, XCD swizzle.
__global__ __launch_bounds__(256) void gemm_out_kernel(const u16* __restrict__ A,
                                                       const u16* __restrict__ Bt,
                                                       const float* __restrict__ bias,
                                                       float* __restrict__ O) {
  __shared__ u16 Asm[2][128 * 64];
  __shared__ u16 Bsm[2][128 * 64];
  const int tid = threadIdx.x;
  const int lane = tid & 63;
  const int wid = tid >> 6;
  const int wr = wid >> 1, wc = wid & 1;
  const int work = (blockIdx.x & 7) * 32 + (blockIdx.x >> 3);
  const int m0 = (work & 31) * 128;
  const int n0 = (work >> 5) * 128;
  const int lrow = lane & 15;
  const int kgrp = (lane >> 4) * 8;

  f32x4 acc[4][4];
#pragma unroll
  for (int i = 0; i < 4; ++i)
#pragma unroll
    for (int j = 0; j < 4; ++j)
#pragma unroll
      for (int r = 0; r < 4; ++r) acc[i][j][r] = 0.f;

  auto STAGE = [&](int kt, int bufi) {
#pragma unroll
    for (int it = 0; it < 4; ++it) {
      const int off = it * 4096 + tid * 16;
      const int row = off >> 7;
      const int col = (off & 127) >> 1;
      gload16(A  + (size_t)(m0 + row) * HID + kt * 64 + col, (char*)Asm[bufi] + off);
      gload16(Bt + (size_t)(n0 + row) * HID + kt * 64 + col, (char*)Bsm[bufi] + off);
    }
  };

  STAGE(0, 0);
  __syncthreads();

  const int NKT = HID / 64;
  for (int kt = 0; kt < NKT; ++kt) {
    const int cur = kt & 1;
    if (kt + 1 < NKT) STAGE(kt + 1, cur ^ 1);

    const u16* Ac = Asm[cur];
    const u16* Bc = Bsm[cur];
#pragma unroll
    for (int kk = 0; kk < 2; ++kk) {
      bf16x8 af[4], bfr[4];
#pragma unroll
      for (int i = 0; i < 4; ++i) {
        af[i]  = *(const bf16x8*)(Ac + (size_t)(wr * 64 + i * 16 + lrow) * 64 + kk * 32 + kgrp);
        bfr[i] = *(const bf16x8*)(Bc + (size_t)(wc * 64 + i * 16 + lrow) * 64 + kk * 32 + kgrp);
      }
#pragma unroll
      for (int i = 0; i < 4; ++i)
#pragma unroll
        for (int j = 0; j < 4; ++j)
          acc[i][j] = __builtin_amdgcn_mfma_f32_16x16x32_bf16(af[i], bfr[j], acc[i][j], 0, 0, 0);
    }
    __syncthreads();
  }

#pragma unroll
  for (int i = 0; i < 4; ++i) {
#pragma unroll
    for (int j = 0; j < 4; ++j) {
      const int rbase = m0 + wr * 64 + i * 16 + (lane >> 4) * 4;
      const int n = n0 + wc * 64 + j * 16 + lrow;
      const float bv = bias[n];
#pragma unroll
      for (int r = 0; r < 4; ++r)
        O[(size_t)(rbase + r) * HID + n] = acc[i][j][r] + bv;
    }
  }
}

// ------------------------------------------------------------ flash attention
// 8 waves x 512 threads, 16 q-rows/wave (same blocks/K-traffic as r6; 2x
// waves/SIMD so one wave's exp2 chain overlaps another's MFMA). setprio(1)
// around MFMA clusters (T5, attn-positive per m191). Otherwise r6 structure:
// QBLK=128 (512 blocks), XCD-confined heads, dbuf K/V, fixed-max exp2
// softmax, ones-MFMA row-sum, XOR-swizzled K/V LDS.
__global__ __launch_bounds__(512) void attn_kernel(const u16* __restrict__ Q,
                                                   const u16* __restrict__ K,
                                                   const u16* __restrict__ Vt,
                                                   const float* __restrict__ msk,
                                                   u16* __restrict__ ctx) {
  __shared__ u16 Ks[2][64 * 64];    // [buf][key][d], swizzled
  __shared__ u16 Vs[2][64 * 64];    // [buf][d][key], swizzled
  __shared__ u16 Ps[8][16 * 72];    // per-wave P (16 q-rows), padded rows
  const int bid = blockIdx.x;
  const int xcd = bid & 7;
  const int idx = bid >> 3;               // 0..63
  const int bh = xcd * 4 + (idx & 3);
  const int q0 = (idx >> 2) * 128;
  const int b = bh >> 4, h = bh & 15;
  const int tid = threadIdx.x, lane = tid & 63, wid = tid >> 6;
  const int lrow = lane & 15;
  const int kgrp = (lane >> 4) * 8;
  const u16* Qp = Q + (size_t)bh * SEQ * HD;
  const u16* Kp = K + (size_t)bh * SEQ * HD;
  const u16* Vp = Vt + (size_t)bh * HD * SEQ;

  bf16x8 vones;
#pragma unroll
  for (int i = 0; i < 8; ++i) vones[i] = (short)0x3F80;

  // wave owns 16 q-rows
  bf16x8 qf[2];
#pragma unroll
  for (int kk = 0; kk < 2; ++kk)
    qf[kk] = *(const bf16x8*)(Qp + (size_t)(q0 + wid * 16 + lrow) * HD + kk * 32 + kgrp);

  f32x4 acc[4], acc_l;
#pragma unroll
  for (int r = 0; r < 4; ++r) acc_l[r] = 0.f;
#pragma unroll
  for (int df = 0; df < 4; ++df)
#pragma unroll
    for (int r = 0; r < 4; ++r) acc[df][r] = 0.f;

  // 512 threads: one 16B slot each per 8KB tile
  auto STAGE = [&](int s0, int bufi) {
    const int off = tid * 16;
    const int row = off >> 7;
    const int w = off & 127;
    const int col = (w ^ ((row & 7) << 4)) >> 1;
    gload16(Kp + (size_t)(s0 + row) * HD + col, (char*)Ks[bufi] + off);
    gload16(Vp + (size_t)row * SEQ + s0 + col, (char*)Vs[bufi] + off);
  };

  STAGE(0, 0);
  __syncthreads();

  const int NT = SEQ / 64;
  for (int t = 0; t < NT; ++t) {
    const int cur = t & 1;
    if (t + 1 < NT) STAGE((t + 1) * 64, cur ^ 1);

    const u16* Kc = Ks[cur];
    const u16* Vc = Vs[cur];
    const int s0 = t * 64;

    // S' = Qs K^T
    f32x4 sf[4];
#pragma unroll
    for (int c = 0; c < 4; ++c)
#pragma unroll
      for (int r = 0; r < 4; ++r) sf[c][r] = 0.f;
#pragma unroll
    for (int kk = 0; kk < 2; ++kk) {
      bf16x8 kf[4];
#pragma unroll
      for (int c = 0; c < 4; ++c) {
        const int row = c * 16 + lrow;
        const int byteoff = row * 128 + ((kk * 64 + (lane >> 4) * 16) ^ ((row & 7) << 4));
        kf[c] = *(const bf16x8*)((const char*)Kc + byteoff);
      }
      __builtin_amdgcn_s_setprio(1);
#pragma unroll
      for (int c = 0; c < 4; ++c)
        sf[c] = __builtin_amdgcn_mfma_f32_16x16x32_bf16(qf[kk], kf[c], sf[c], 0, 0, 0);
      __builtin_amdgcn_s_setprio(0);
    }

    float addm[4];
#pragma unroll
    for (int c = 0; c < 4; ++c)
      addm[c] = (1.0f - msk[b * SEQ + s0 + c * 16 + lrow]) * MASK_L2E;

#pragma unroll
    for (int c = 0; c < 4; ++c)
#pragma unroll
      for (int r = 0; r < 4; ++r)
        sf[c][r] = __builtin_exp2f(sf[c][r] + addm[c]);
#pragma unroll
    for (int r = 0; r < 4; ++r) {
      const int row = (lane >> 4) * 4 + r;
      const unsigned w01 = pk2(sf[0][r], sf[1][r]);
      const unsigned w23 = pk2(sf[2][r], sf[3][r]);
      u16* base = &Ps[wid][(size_t)row * 72 + lrow];
      base[0]  = (u16)w01;
      base[16] = (u16)(w01 >> 16);
      base[32] = (u16)w23;
      base[48] = (u16)(w23 >> 16);
    }

    // ctx += P V ; l += P @ 1
#pragma unroll
    for (int kk = 0; kk < 2; ++kk) {
      bf16x8 pf, vf[4];
      pf = *(const bf16x8*)(&Ps[wid][(size_t)lrow * 72 + kk * 32 + kgrp]);
#pragma unroll
      for (int df = 0; df < 4; ++df) {
        const int row = df * 16 + lrow;
        const int byteoff = row * 128 + ((kk * 64 + (lane >> 4) * 16) ^ ((row & 7) << 4));
        vf[df] = *(const bf16x8*)((const char*)Vc + byteoff);
      }
      __builtin_amdgcn_s_setprio(1);
#pragma unroll
      for (int df = 0; df < 4; ++df)
        acc[df] = __builtin_amdgcn_mfma_f32_16x16x32_bf16(pf, vf[df], acc[df], 0, 0, 0);
      acc_l = __builtin_amdgcn_mfma_f32_16x16x32_bf16(pf, vones, acc_l, 0, 0, 0);
      __builtin_amdgcn_s_setprio(0);
    }

    __syncthreads();
  }

  f32x4 rl;
#pragma unroll
  for (int r = 0; r < 4; ++r) rl[r] = 1.0f / acc_l[r];
#pragma unroll
  for (int df = 0; df < 4; ++df)
#pragma unroll
    for (int r = 0; r < 4; ++r) {
      const int s = q0 + wid * 16 + (lane >> 4) * 4 + r;
      const int d = df * 16 + lrow;
      ctx[((size_t)(b * SEQ + s)) * HID + h * HD + d] = f2b(acc[df][r] * rl[r]);
    }
}

// ---------------------------------------------------------------- launch
extern "C" void kernel_launch(void* const* d_in, const int* in_sizes, int n_in,
                              void* d_out, int out_size, void* d_ws, size_t ws_size,
                              hipStream_t stream) {
  const float* X    = (const float*)d_in[0];
  const float* msk  = (const float*)d_in[1];
  const float* Wq   = (const float*)d_in[2];
  const float* bq   = (const float*)d_in[3];
  const float* Wk   = (const float*)d_in[4];
  const float* bk   = (const float*)d_in[5];
  const float* Wv   = (const float*)d_in[6];
  const float* bv   = (const float*)d_in[7];
  const float* Wo   = (const float*)d_in[8];
  const float* bo   = (const float*)d_in[9];
  float* out = (float*)d_out;
  char* ws = (char*)d_ws;

  const size_t MB = 1u << 20;
  u16* XB   = (u16*)(ws);              //  8 MB  [MROWS][HID]
  u16* WTq  = (u16*)(ws +  8 * MB);    //  2 MB each; WTq|WTk|WTv contiguous
  u16* WTk  = (u16*)(ws + 10 * MB);
  u16* WTv  = (u16*)(ws + 12 * MB);
  u16* WTo  = (u16*)(ws + 14 * MB);
  u16* Qb   = (u16*)(ws + 16 * MB);    //  8 MB  [B,NH,S,HD] (pre-scaled)
  u16* Kb   = (u16*)(ws + 24 * MB);    //  8 MB  [B,NH,S,HD]
  u16* VTb  = (u16*)(ws + 32 * MB);    //  8 MB  [B,NH,HD,S]
  u16* CTXb = (u16*)(ws + 40 * MB);    //  8 MB  [B,S,HID]

  castx_kernel<<<dim3(MROWS * HID / 4 / 256), dim3(256), 0, stream>>>(X, XB);
  wtrans4_kernel<<<dim3(HID / 32, HID / 32, 4), dim3(32, 8), 0, stream>>>(
      Wq, Wk, Wv, Wo, WTq, WTk, WTv, WTo);

  gemm_qkv_kernel<<<dim3(192), dim3(512), 0, stream>>>(
      XB, WTq, bq, bk, bv, Qb, Kb, VTb);

  attn_kernel<<<dim3(512), dim3(512), 0, stream>>>(Qb, Kb, VTb, msk, CTXb);

  gemm_out_kernel<<<dim3(256), dim3(256), 0, stream>>>(CTXb, WTo, bo, out);
}